// Round 1
// baseline (187.620 us; speedup 1.0000x reference)
//
#include <hip/hip_runtime.h>
#include <hip/hip_bf16.h>

// Bilinear: out[s,i,j] = sum_{d,e} t1[s,i,d] * K[d,e] * t0[s,j,e] + bias
// S=8, N=2048, D=256.
// Strategy: bf16 MFMA (threshold 1.92 permits), two NT GEMMs:
//   Q[s,j,d]  = sum_e t0[s,j,e] * K[d,e]          (prep, bf16 out)
//   out[s,i,j] = sum_d t1[s,i,d] * Q[s,j,d] + b   (main, fp32 out)

typedef __bf16 bf16x8 __attribute__((ext_vector_type(8)));
typedef float f32x4 __attribute__((ext_vector_type(4)));

__device__ __forceinline__ unsigned short f2bf(float f) {
  union { __hip_bfloat16 h; unsigned short u; } v;
  v.h = __float2bfloat16(f);
  return v.u;
}

// Convert t0 (4M), t1 (4M), kernel (64K) fp32 -> bf16 into workspace.
__global__ __launch_bounds__(256) void cvt3(const float4* __restrict__ t0,
                                            const float4* __restrict__ t1,
                                            const float4* __restrict__ kk,
                                            ushort4* __restrict__ o0,
                                            ushort4* __restrict__ o1,
                                            ushort4* __restrict__ ok) {
  const int stride = gridDim.x * blockDim.x;
  const int i0 = blockIdx.x * blockDim.x + threadIdx.x;
  for (int j = i0; j < 1048576; j += stride) {
    float4 v = t0[j];
    o0[j] = make_ushort4(f2bf(v.x), f2bf(v.y), f2bf(v.z), f2bf(v.w));
  }
  for (int j = i0; j < 1048576; j += stride) {
    float4 v = t1[j];
    o1[j] = make_ushort4(f2bf(v.x), f2bf(v.y), f2bf(v.z), f2bf(v.w));
  }
  for (int j = i0; j < 16384; j += stride) {
    float4 v = kk[j];
    ok[j] = make_ushort4(f2bf(v.x), f2bf(v.y), f2bf(v.z), f2bf(v.w));
  }
}

// NT GEMM: C[m][n] = sum_k A[m][k]*B[n][k] (+bias), A,B bf16 row-major [rows][K].
// 128x128 tile, BK=32, 256 threads = 4 waves, each wave a 64x64 subtile of
// 4x4 mfma_f32_16x16x32_bf16. Staging via global_load_lds width=16
// (wave-uniform LDS base + lane*16 => row-major [128][32] bf16 tiles).
template <bool OUT_BF16>
__global__ __launch_bounds__(256, 2) void gemm_nt(
    const unsigned short* __restrict__ A, const unsigned short* __restrict__ B,
    void* __restrict__ Cout, const float* __restrict__ bias,
    const int K, const int ldc,
    const long long aStride, const long long bStride, const long long cStride) {
  __shared__ unsigned short sA[128 * 32];
  __shared__ unsigned short sB[128 * 32];

  const int tid = threadIdx.x;
  const int wave = tid >> 6;
  const int lane = tid & 63;
  const int quad = lane >> 4;
  const int l16 = lane & 15;
  const int wrow = (wave >> 1) * 64;  // wave's 64x64 subtile origin
  const int wcol = (wave & 1) * 64;

  const int brow = blockIdx.y * 128;
  const int bcol = blockIdx.x * 128;
  const long long bz = blockIdx.z;

  const unsigned short* Ab = A + bz * aStride + (long long)brow * K;
  const unsigned short* Bb = B + bz * bStride + (long long)bcol * K;

  // staging: lane -> (row = half*64 + wave*16 + lane/4, col = (lane&3)*8)
  const int srow = wave * 16 + (lane >> 2);
  const int scol = (lane & 3) * 8;

  f32x4 acc[4][4];
#pragma unroll
  for (int i = 0; i < 4; i++)
#pragma unroll
    for (int j = 0; j < 4; j++) acc[i][j] = (f32x4){0.f, 0.f, 0.f, 0.f};

  for (int kt = 0; kt < K; kt += 32) {
    __syncthreads();  // previous iteration's ds_reads done before overwrite
#pragma unroll
    for (int half = 0; half < 2; half++) {
      const unsigned short* ga = Ab + (long long)(half * 64 + srow) * K + kt + scol;
      const unsigned short* gb = Bb + (long long)(half * 64 + srow) * K + kt + scol;
      unsigned short* la = &sA[(half * 64 + wave * 16) * 32];  // wave-uniform
      unsigned short* lb = &sB[(half * 64 + wave * 16) * 32];
      __builtin_amdgcn_global_load_lds(
          (const __attribute__((address_space(1))) unsigned int*)ga,
          (__attribute__((address_space(3))) unsigned int*)la, 16, 0, 0);
      __builtin_amdgcn_global_load_lds(
          (const __attribute__((address_space(1))) unsigned int*)gb,
          (__attribute__((address_space(3))) unsigned int*)lb, 16, 0, 0);
    }
    __syncthreads();  // staging complete

    bf16x8 af[4], bfr[4];
#pragma unroll
    for (int mi = 0; mi < 4; mi++)
      af[mi] = *(const bf16x8*)&sA[(wrow + mi * 16 + l16) * 32 + quad * 8];
#pragma unroll
    for (int ni = 0; ni < 4; ni++)
      bfr[ni] = *(const bf16x8*)&sB[(wcol + ni * 16 + l16) * 32 + quad * 8];
#pragma unroll
    for (int mi = 0; mi < 4; mi++)
#pragma unroll
      for (int ni = 0; ni < 4; ni++)
        acc[mi][ni] = __builtin_amdgcn_mfma_f32_16x16x32_bf16(af[mi], bfr[ni],
                                                              acc[mi][ni], 0, 0, 0);
  }

  // C/D frag mapping (m89-verified): col = lane&15, row = quad*4 + reg
  if constexpr (OUT_BF16) {
    unsigned short* C = (unsigned short*)Cout + bz * cStride;
#pragma unroll
    for (int mi = 0; mi < 4; mi++)
#pragma unroll
      for (int ni = 0; ni < 4; ni++) {
        const int r0 = brow + wrow + mi * 16 + quad * 4;
        const int c = bcol + wcol + ni * 16 + l16;
#pragma unroll
        for (int r = 0; r < 4; r++)
          C[(long long)(r0 + r) * ldc + c] = f2bf(acc[mi][ni][r]);
      }
  } else {
    const float bv = bias[0];
    float* C = (float*)Cout + bz * cStride;
#pragma unroll
    for (int mi = 0; mi < 4; mi++)
#pragma unroll
      for (int ni = 0; ni < 4; ni++) {
        const int r0 = brow + wrow + mi * 16 + quad * 4;
        const int c = bcol + wcol + ni * 16 + l16;
#pragma unroll
        for (int r = 0; r < 4; r++)
          C[(long long)(r0 + r) * ldc + c] = acc[mi][ni][r] + bv;
      }
  }
}

extern "C" void kernel_launch(void* const* d_in, const int* in_sizes, int n_in,
                              void* d_out, int out_size, void* d_ws, size_t ws_size,
                              hipStream_t stream) {
  const float* t0 = (const float*)d_in[0];    // [8,2048,256]
  const float* t1 = (const float*)d_in[1];    // [8,2048,256]
  const float* kk = (const float*)d_in[2];    // [256,256]
  const float* bias = (const float*)d_in[3];  // [1]

  // ws layout (bf16 elements): T0b 4M | T1b 4M | Kb 64K | Qb 4M  = 24.2 MiB
  unsigned short* T0b = (unsigned short*)d_ws;
  unsigned short* T1b = T0b + 4194304;
  unsigned short* Kb = T1b + 4194304;
  unsigned short* Qb = Kb + 65536;

  cvt3<<<4096, 256, 0, stream>>>((const float4*)t0, (const float4*)t1,
                                 (const float4*)kk, (ushort4*)T0b,
                                 (ushort4*)T1b, (ushort4*)Kb);

  // Q[s*N+j][d] = sum_e t0[s,j,e]*K[d,e]  : M=16384, N=256, K=256
  gemm_nt<true><<<dim3(2, 128, 1), 256, 0, stream>>>(T0b, Kb, Qb, nullptr, 256,
                                                     256, 0, 0, 0);

  // out[s][i][j] = sum_d t1[s,i,d]*Q[s,j,d] + bias : per-s 2048x2048, K=256
  gemm_nt<false><<<dim3(16, 16, 8), 256, 0, stream>>>(
      T1b, Qb, d_out, bias, 256, 2048, 524288LL, 524288LL, 4194304LL);
}

// Round 2
// 186.413 us; speedup vs baseline: 1.0065x; 1.0065x over previous
//
#include <hip/hip_runtime.h>
#include <hip/hip_bf16.h>

// Bilinear: out[s,i,j] = sum_{d,e} t1[s,i,d] * K[d,e] * t0[s,j,e] + bias
// S=8, N=2048, D=256.
// bf16 MFMA, two NT GEMMs:
//   Q[s,j,d]   = sum_e t0[s,j,e] * K[d,e]         (prep, bf16 out)
//   out[s,i,j] = sum_d t1[s,i,d] * Q[s,j,d] + b   (main, fp32 out)
// R2: ping-pong LDS double-buffer, ONE barrier per BK=32 step; next tile's
// global_load_lds issued between current tile's ds_reads and MFMAs so the
// vmcnt(0) drain at the next barrier overlaps a full compute phase.

typedef __bf16 bf16x8 __attribute__((ext_vector_type(8)));
typedef float f32x4 __attribute__((ext_vector_type(4)));

__device__ __forceinline__ unsigned short f2bf(float f) {
  union { __hip_bfloat16 h; unsigned short u; } v;
  v.h = __float2bfloat16(f);
  return v.u;
}

// Convert t0 (4M), t1 (4M), kernel (64K) fp32 -> bf16 into workspace.
__global__ __launch_bounds__(256) void cvt3(const float4* __restrict__ t0,
                                            const float4* __restrict__ t1,
                                            const float4* __restrict__ kk,
                                            ushort4* __restrict__ o0,
                                            ushort4* __restrict__ o1,
                                            ushort4* __restrict__ ok) {
  const int stride = gridDim.x * blockDim.x;
  const int i0 = blockIdx.x * blockDim.x + threadIdx.x;
  for (int j = i0; j < 1048576; j += stride) {
    float4 v = t0[j];
    o0[j] = make_ushort4(f2bf(v.x), f2bf(v.y), f2bf(v.z), f2bf(v.w));
  }
  for (int j = i0; j < 1048576; j += stride) {
    float4 v = t1[j];
    o1[j] = make_ushort4(f2bf(v.x), f2bf(v.y), f2bf(v.z), f2bf(v.w));
  }
  for (int j = i0; j < 16384; j += stride) {
    float4 v = kk[j];
    ok[j] = make_ushort4(f2bf(v.x), f2bf(v.y), f2bf(v.z), f2bf(v.w));
  }
}

// NT GEMM: C[m][n] = sum_k A[m][k]*B[n][k] (+bias), A,B bf16 row-major [rows][K].
// 128x128 tile, BK=32 ping-pong, 256 threads = 4 waves, each wave a 64x64
// subtile of 4x4 mfma_f32_16x16x32_bf16. K must be a multiple of 64.
template <bool OUT_BF16>
__global__ __launch_bounds__(256, 2) void gemm_nt(
    const unsigned short* __restrict__ A, const unsigned short* __restrict__ B,
    void* __restrict__ Cout, const float* __restrict__ bias,
    const int K, const int ldc,
    const long long aStride, const long long bStride, const long long cStride) {
  __shared__ unsigned short sA[2][128 * 32];
  __shared__ unsigned short sB[2][128 * 32];

  const int tid = threadIdx.x;
  const int wave = tid >> 6;
  const int lane = tid & 63;
  const int quad = lane >> 4;
  const int l16 = lane & 15;
  const int wrow = (wave >> 1) * 64;  // wave's 64x64 subtile origin
  const int wcol = (wave & 1) * 64;

  const int brow = blockIdx.y * 128;
  const int bcol = blockIdx.x * 128;
  const long long bz = blockIdx.z;

  const unsigned short* Ab = A + bz * aStride + (long long)brow * K;
  const unsigned short* Bb = B + bz * bStride + (long long)bcol * K;

  // staging: lane -> (row = half*64 + wave*16 + lane/4, col = (lane&3)*8);
  // LDS dest is wave-uniform base + lane*16B => row-major [128][32] tile.
  const int srow = wave * 16 + (lane >> 2);
  const int scol = (lane & 3) * 8;

  auto stage = [&](unsigned short* dA, unsigned short* dB, int kt) {
#pragma unroll
    for (int half = 0; half < 2; half++) {
      const unsigned short* ga = Ab + (long long)(half * 64 + srow) * K + kt + scol;
      const unsigned short* gb = Bb + (long long)(half * 64 + srow) * K + kt + scol;
      __builtin_amdgcn_global_load_lds(
          (const __attribute__((address_space(1))) unsigned int*)ga,
          (__attribute__((address_space(3))) unsigned int*)(dA + (half * 64 + wave * 16) * 32),
          16, 0, 0);
      __builtin_amdgcn_global_load_lds(
          (const __attribute__((address_space(1))) unsigned int*)gb,
          (__attribute__((address_space(3))) unsigned int*)(dB + (half * 64 + wave * 16) * 32),
          16, 0, 0);
    }
  };

  f32x4 acc[4][4];
#pragma unroll
  for (int i = 0; i < 4; i++)
#pragma unroll
    for (int j = 0; j < 4; j++) acc[i][j] = (f32x4){0.f, 0.f, 0.f, 0.f};

  stage(sA[0], sB[0], 0);  // prologue: tile 0 in flight; acc-init overlaps

  for (int kt = 0; kt < K; kt += 64) {
    // ---- tile at kt, buffer 0 ----
    __syncthreads();  // drains vmcnt: buf0 staged; all prior buf-reads done
    {
      bf16x8 af[4], bfr[4];
#pragma unroll
      for (int mi = 0; mi < 4; mi++)
        af[mi] = *(const bf16x8*)&sA[0][(wrow + mi * 16 + l16) * 32 + quad * 8];
#pragma unroll
      for (int ni = 0; ni < 4; ni++)
        bfr[ni] = *(const bf16x8*)&sB[0][(wcol + ni * 16 + l16) * 32 + quad * 8];
      stage(sA[1], sB[1], kt + 32);  // K%64==0 => kt+32 < K always
#pragma unroll
      for (int mi = 0; mi < 4; mi++)
#pragma unroll
        for (int ni = 0; ni < 4; ni++)
          acc[mi][ni] = __builtin_amdgcn_mfma_f32_16x16x32_bf16(
              af[mi], bfr[ni], acc[mi][ni], 0, 0, 0);
    }
    // ---- tile at kt+32, buffer 1 ----
    __syncthreads();
    {
      bf16x8 af[4], bfr[4];
#pragma unroll
      for (int mi = 0; mi < 4; mi++)
        af[mi] = *(const bf16x8*)&sA[1][(wrow + mi * 16 + l16) * 32 + quad * 8];
#pragma unroll
      for (int ni = 0; ni < 4; ni++)
        bfr[ni] = *(const bf16x8*)&sB[1][(wcol + ni * 16 + l16) * 32 + quad * 8];
      if (kt + 64 < K) stage(sA[0], sB[0], kt + 64);
#pragma unroll
      for (int mi = 0; mi < 4; mi++)
#pragma unroll
        for (int ni = 0; ni < 4; ni++)
          acc[mi][ni] = __builtin_amdgcn_mfma_f32_16x16x32_bf16(
              af[mi], bfr[ni], acc[mi][ni], 0, 0, 0);
    }
  }

  // C/D frag mapping (m89-verified): col = lane&15, row = quad*4 + reg
  if constexpr (OUT_BF16) {
    unsigned short* C = (unsigned short*)Cout + bz * cStride;
#pragma unroll
    for (int mi = 0; mi < 4; mi++)
#pragma unroll
      for (int ni = 0; ni < 4; ni++) {
        const int r0 = brow + wrow + mi * 16 + quad * 4;
        const int c = bcol + wcol + ni * 16 + l16;
#pragma unroll
        for (int r = 0; r < 4; r++)
          C[(long long)(r0 + r) * ldc + c] = f2bf(acc[mi][ni][r]);
      }
  } else {
    const float bv = bias[0];
    float* C = (float*)Cout + bz * cStride;
#pragma unroll
    for (int mi = 0; mi < 4; mi++)
#pragma unroll
      for (int ni = 0; ni < 4; ni++) {
        const int r0 = brow + wrow + mi * 16 + quad * 4;
        const int c = bcol + wcol + ni * 16 + l16;
#pragma unroll
        for (int r = 0; r < 4; r++)
          C[(long long)(r0 + r) * ldc + c] = acc[mi][ni][r] + bv;
      }
  }
}

extern "C" void kernel_launch(void* const* d_in, const int* in_sizes, int n_in,
                              void* d_out, int out_size, void* d_ws, size_t ws_size,
                              hipStream_t stream) {
  const float* t0 = (const float*)d_in[0];    // [8,2048,256]
  const float* t1 = (const float*)d_in[1];    // [8,2048,256]
  const float* kk = (const float*)d_in[2];    // [256,256]
  const float* bias = (const float*)d_in[3];  // [1]

  // ws layout (bf16 elements): T0b 4M | T1b 4M | Kb 64K | Qb 4M  = 24.2 MiB
  unsigned short* T0b = (unsigned short*)d_ws;
  unsigned short* T1b = T0b + 4194304;
  unsigned short* Kb = T1b + 4194304;
  unsigned short* Qb = Kb + 65536;

  cvt3<<<4096, 256, 0, stream>>>((const float4*)t0, (const float4*)t1,
                                 (const float4*)kk, (ushort4*)T0b,
                                 (ushort4*)T1b, (ushort4*)Kb);

  // Q[s*N+j][d] = sum_e t0[s,j,e]*K[d,e]  : M=16384, N=256, K=256
  gemm_nt<true><<<dim3(2, 128, 1), 256, 0, stream>>>(T0b, Kb, Qb, nullptr, 256,
                                                     256, 0, 0, 0);

  // out[s][i][j] = sum_d t1[s,i,d]*Q[s,j,d] + bias : per-s 2048x2048, K=256
  gemm_nt<false><<<dim3(16, 16, 8), 256, 0, stream>>>(
      T1b, Qb, d_out, bias, 256, 2048, 524288LL, 524288LL, 4194304LL);
}